// Round 3
// baseline (6443.125 us; speedup 1.0000x reference)
//
#include <hip/hip_runtime.h>

#define HH 8
#define FIN 64

// ---------- helpers ----------
__device__ __forceinline__ float b2f(unsigned short u) {
  union { unsigned int i; float f; } x;
  x.i = ((unsigned int)u) << 16;
  return x.f;
}

__device__ __forceinline__ float lrelu(float x) { return x > 0.f ? x : 0.2f * x; }

// dtype-agnostic scalar load: isf=1 -> fp32 array, isf=0 -> bf16 array
__device__ __forceinline__ float ld(const void* p, int i, int isf) {
  return isf ? ((const float*)p)[i] : b2f(((const unsigned short*)p)[i]);
}

// CAS-based float add: correct on any memory class / compile flags
__device__ __forceinline__ void atomicAddF(float* addr, float v) {
  unsigned int* p = (unsigned int*)addr;
  unsigned int old = *p;
  while (true) {
    unsigned int assumed = old;
    float f = __uint_as_float(assumed) + v;
    old = atomicCAS(p, assumed, __float_as_uint(f));
    if (old == assumed) break;
  }
}

// ---------- dtype detection ----------
// Interpret first 2048 u16 of x as bf16. True bf16 ~N(0,1): exponent field
// < 0x90 always. fp32 read as u16 pairs: even slots are mantissa garbage,
// ~43% have exponent-field >= 0x90. Flag fp32 if count >= 8.
__global__ void detect_kernel(const unsigned short* __restrict__ x, int* __restrict__ flag) {
  __shared__ int s[256];
  int t = threadIdx.x;
  int cnt = 0;
  for (int i = t; i < 2048; i += 256) {
    int e = (x[i] >> 7) & 0xFF;
    if (e >= 0x90) cnt++;
  }
  s[t] = cnt;
  __syncthreads();
  for (int k = 128; k > 0; k >>= 1) {
    if (t < k) s[t] += s[t + k];
    __syncthreads();
  }
  if (t == 0) flag[0] = (s[0] >= 8) ? 1 : 0;
}

// ---------- fill ----------
__global__ void fill_u32(unsigned int* __restrict__ p, long long n, unsigned int v) {
  long long i = (long long)blockIdx.x * blockDim.x + threadIdx.x;
  if (i < n) p[i] = v;
}

// ---------- projection: h = x @ W + b, plus up to 3 attention dot-products ----------
__global__ void proj_kernel(const void* __restrict__ x,
                            const void* __restrict__ W,
                            const void* __restrict__ b,
                            float* __restrict__ h, int N,
                            const void* __restrict__ a0v, float* __restrict__ s0,
                            const void* __restrict__ a1v, float* __restrict__ s1,
                            const void* __restrict__ a2v, float* __restrict__ s2,
                            const int* __restrict__ flag) {
  __shared__ float Wl[FIN][HH];
  __shared__ float bl[HH];
  __shared__ float al[3][HH];
  int isf = flag[0];
  int t = threadIdx.x;
  for (int i = t; i < FIN * HH; i += blockDim.x) Wl[i >> 3][i & 7] = ld(W, i, isf);
  if (t < HH) {
    bl[t] = ld(b, t, isf);
    al[0][t] = a0v ? ld(a0v, t, isf) : 0.f;
    al[1][t] = a1v ? ld(a1v, t, isf) : 0.f;
    al[2][t] = a2v ? ld(a2v, t, isf) : 0.f;
  }
  __syncthreads();
  int n = blockIdx.x * blockDim.x + t;
  if (n >= N) return;
  float acc[HH];
#pragma unroll
  for (int j = 0; j < HH; ++j) acc[j] = bl[j];
  if (isf) {
    const float4* xr = (const float4*)((const float*)x + (size_t)n * FIN);
#pragma unroll
    for (int v = 0; v < FIN / 4; ++v) {
      float4 p = xr[v];
      float f4[4] = {p.x, p.y, p.z, p.w};
#pragma unroll
      for (int k = 0; k < 4; ++k) {
        int f = v * 4 + k;
#pragma unroll
        for (int j = 0; j < HH; ++j) acc[j] += f4[k] * Wl[f][j];
      }
    }
  } else {
    const uint4* xr = (const uint4*)((const unsigned short*)x + (size_t)n * FIN);
#pragma unroll
    for (int v = 0; v < FIN / 8; ++v) {
      uint4 p = xr[v];
      unsigned int w[4] = {p.x, p.y, p.z, p.w};
#pragma unroll
      for (int k = 0; k < 4; ++k) {
        float f0 = __uint_as_float(w[k] << 16);
        float f1 = __uint_as_float(w[k] & 0xFFFF0000u);
        int f = v * 8 + k * 2;
#pragma unroll
        for (int j = 0; j < HH; ++j) acc[j] += f0 * Wl[f][j];
#pragma unroll
        for (int j = 0; j < HH; ++j) acc[j] += f1 * Wl[f + 1][j];
      }
    }
  }
  float* hn = h + (size_t)n * HH;
#pragma unroll
  for (int j = 0; j < HH; ++j) hn[j] = acc[j];
  float d0 = 0.f, d1 = 0.f, d2 = 0.f;
#pragma unroll
  for (int j = 0; j < HH; ++j) {
    d0 += acc[j] * al[0][j];
    d1 += acc[j] * al[1][j];
    d2 += acc[j] * al[2][j];
  }
  if (s0) s0[n] = d0;
  if (s1) s1[n] = d1;
  if (s2) s2[n] = d2;
}

// ---------- GAT edge passes (no max-shift: alpha is O(+-8), exp is fp32-safe) ----------
__global__ void edge_sum(const int* __restrict__ ei, int E,
                         const float* __restrict__ as, const float* __restrict__ ad,
                         float* __restrict__ den) {
  int e = blockIdx.x * blockDim.x + threadIdx.x;
  if (e >= E) return;
  int r = ei[e], c = ei[E + e];
  float a = lrelu(as[r] + ad[c]);
  atomicAddF(&den[c], __expf(a));
}

__global__ void edge_out(const int* __restrict__ ei, int E,
                         const float* __restrict__ as, const float* __restrict__ ad,
                         const float* __restrict__ den,
                         const float* __restrict__ h_src, float* __restrict__ out) {
  long long t = (long long)blockIdx.x * blockDim.x + threadIdx.x;
  int e = (int)(t >> 3);
  if (e >= E) return;
  int j = (int)(t & 7);
  int r = ei[e], c = ei[E + e];
  float a = lrelu(as[r] + ad[c]);
  float w = __expf(a) / (den[c] + 1e-16f);
  atomicAddF(&out[(size_t)c * HH + j], h_src[(size_t)r * HH + j] * w);
}

// ---------- semantic attention score: sum_n tanh(relu(o[n]) @ kW + kb) . q ----------
__global__ void score_kernel(const float* __restrict__ o0, const float* __restrict__ o1, int N,
                             const void* __restrict__ kW,
                             const void* __restrict__ kb,
                             const void* __restrict__ qv,
                             float* __restrict__ score,
                             const int* __restrict__ flag) {
  __shared__ float kWl[HH][HH];
  __shared__ float kbl[HH], ql[HH];
  __shared__ float red0[256], red1[256];
  int isf = flag[0];
  int t = threadIdx.x;
  if (t < HH * HH) kWl[t >> 3][t & 7] = ld(kW, t, isf);
  if (t < HH) { kbl[t] = ld(kb, t, isf); ql[t] = ld(qv, t, isf); }
  __syncthreads();
  int n = blockIdx.x * blockDim.x + t;
  float s0 = 0.f, s1 = 0.f;
  if (n < N) {
    const float* p0 = o0 + (size_t)n * HH;
    const float* p1 = o1 + (size_t)n * HH;
    float v0[HH], v1[HH];
#pragma unroll
    for (int j = 0; j < HH; ++j) { v0[j] = fmaxf(p0[j], 0.f); v1[j] = fmaxf(p1[j], 0.f); }
#pragma unroll
    for (int j = 0; j < HH; ++j) {
      float t0 = kbl[j], t1 = kbl[j];
#pragma unroll
      for (int i = 0; i < HH; ++i) { t0 += v0[i] * kWl[i][j]; t1 += v1[i] * kWl[i][j]; }
      s0 += tanhf(t0) * ql[j];
      s1 += tanhf(t1) * ql[j];
    }
  }
  red0[t] = s0; red1[t] = s1;
  __syncthreads();
  for (int s = 128; s > 0; s >>= 1) {
    if (t < s) { red0[t] += red0[t + s]; red1[t] += red1[t + s]; }
    __syncthreads();
  }
  if (t == 0) { atomicAddF(&score[0], red0[0]); atomicAddF(&score[1], red1[0]); }
}

// ---------- softmax over 2 metapaths + prediction head (fp32 output!) ----------
__global__ void pred_kernel(const float* __restrict__ o0, const float* __restrict__ o1, int N,
                            const float* __restrict__ score,
                            const void* __restrict__ linW,
                            const void* __restrict__ linb,
                            float* __restrict__ outp,
                            const int* __restrict__ flag) {
  int isf = flag[0];
  int n = blockIdx.x * blockDim.x + threadIdx.x;
  if (n >= N) return;
  float s0 = score[0] / (float)N, s1 = score[1] / (float)N;
  float mx = fmaxf(s0, s1);
  float e0 = __expf(s0 - mx), e1 = __expf(s1 - mx);
  float inv = 1.f / (e0 + e1);
  float a0 = e0 * inv, a1 = e1 * inv;
  const float* p0 = o0 + (size_t)n * HH;
  const float* p1 = o1 + (size_t)n * HH;
  float acc = ld(linb, 0, isf);
#pragma unroll
  for (int j = 0; j < HH; ++j) {
    float z = a0 * fmaxf(p0[j], 0.f) + a1 * fmaxf(p1[j], 0.f);
    acc += z * ld(linW, j, isf);
  }
  outp[n] = 1.f / (1.f + __expf(-acc));
}

// ---------- launch ----------
extern "C" void kernel_launch(void* const* d_in, const int* in_sizes, int n_in,
                              void* d_out, int out_size, void* d_ws, size_t ws_size,
                              hipStream_t stream) {
  const int N = in_sizes[0] / FIN;

  const void* x_ind = d_in[0];
  const void* x_org = d_in[1];
  const void* x_ext = d_in[2];
  const int* ei_io = (const int*)d_in[3];  int E_io = in_sizes[3] / 2;  // ind->org
  const int* ei_oi = (const int*)d_in[4];  int E_oi = in_sizes[4] / 2;  // org->ind
  const int* ei_ei = (const int*)d_in[5];  int E_ei = in_sizes[5] / 2;  // ext->ind
  const int* ei_eo = (const int*)d_in[6];  int E_eo = in_sizes[6] / 2;  // ext->org
  const void* W_ind = d_in[7];
  const void* b_ind = d_in[8];
  const void* W_org = d_in[9];
  const void* b_org = d_in[10];
  const void* W_ext = d_in[11];
  const void* b_ext = d_in[12];
  const void* att_src_io = d_in[13];
  const void* att_dst_io = d_in[14];
  const void* att_src_oi = d_in[15];
  const void* att_dst_oi = d_in[16];
  const void* att_src_ei = d_in[17];
  const void* att_dst_ei = d_in[18];
  const void* att_src_eo = d_in[19];
  const void* att_dst_eo = d_in[20];
  const void* k_W = d_in[21];
  const void* k_b = d_in[22];
  const void* qv  = d_in[23];
  const void* lin_ind_W = d_in[24];
  const void* lin_ind_b = d_in[25];
  const void* lin_org_W = d_in[26];
  const void* lin_org_b = d_in[27];

  float* out_f = (float*)d_out;

  // workspace layout (floats)
  float* ws = (float*)d_ws;
  size_t off = 0;
  float* h_ind = ws + off; off += (size_t)N * HH;
  float* h_org = ws + off; off += (size_t)N * HH;
  float* h_ext = ws + off; off += (size_t)N * HH;
  float* as_io = ws + off; off += N;   // h_ind . att_src_ind_org
  float* ad_oi = ws + off; off += N;   // h_ind . att_dst_org_ind
  float* ad_ei = ws + off; off += N;   // h_ind . att_dst_ext_ind
  float* as_oi = ws + off; off += N;   // h_org . att_src_org_ind
  float* ad_io = ws + off; off += N;   // h_org . att_dst_ind_org
  float* ad_eo = ws + off; off += N;   // h_org . att_dst_ext_org
  float* as_ei = ws + off; off += N;   // h_ext . att_src_ext_ind
  float* as_eo = ws + off; off += N;   // h_ext . att_src_ext_org
  float* den_all = ws + off; off += (size_t)4 * N;       // per-mp denom
  float* out_all = ws + off; off += (size_t)4 * N * HH;  // per-mp aggregated [N,8]
  float* score_all = ws + off; off += 4;                 // 2 groups x 2 metapaths
  int* flag = (int*)(ws + off); off += 1;                // dtype flag

  const int BS = 256;
  const int nb_node = (N + BS - 1) / BS;

  detect_kernel<<<1, BS, 0, stream>>>((const unsigned short*)x_ind, flag);

  // zero den_all, out_all, score_all (contiguous)
  {
    long long nz = (long long)4 * N + (long long)4 * N * HH + 4;
    fill_u32<<<(int)((nz + BS - 1) / BS), BS, 0, stream>>>((unsigned int*)den_all, nz, 0u);
  }

  // projections + per-node attention scalars
  proj_kernel<<<nb_node, BS, 0, stream>>>(x_ind, W_ind, b_ind, h_ind, N,
                                          att_src_io, as_io, att_dst_oi, ad_oi, att_dst_ei, ad_ei, flag);
  proj_kernel<<<nb_node, BS, 0, stream>>>(x_org, W_org, b_org, h_org, N,
                                          att_src_oi, as_oi, att_dst_io, ad_io, att_dst_eo, ad_eo, flag);
  proj_kernel<<<nb_node, BS, 0, stream>>>(x_ext, W_ext, b_ext, h_ext, N,
                                          att_src_ei, as_ei, att_src_eo, as_eo,
                                          (const void*)nullptr, (float*)nullptr, flag);

  // metapath table: mp0 org->ind, mp1 ext->ind, mp2 ind->org, mp3 ext->org
  const int* eis[4]      = {ei_oi, ei_ei, ei_io, ei_eo};
  int        Es[4]       = {E_oi, E_ei, E_io, E_eo};
  const float* ass[4]    = {as_oi, as_ei, as_io, as_eo};
  const float* ads[4]    = {ad_oi, ad_ei, ad_io, ad_eo};
  const float* hsrcs[4]  = {h_org, h_ext, h_ind, h_ext};

  for (int mp = 0; mp < 4; ++mp) {
    int E = Es[mp];
    float* den = den_all + (size_t)mp * N;
    float* out = out_all + (size_t)mp * N * HH;
    int nbE  = (E + BS - 1) / BS;
    int nbE8 = (int)(((long long)E * HH + BS - 1) / BS);
    edge_sum<<<nbE, BS, 0, stream>>>(eis[mp], E, ass[mp], ads[mp], den);
    edge_out<<<nbE8, BS, 0, stream>>>(eis[mp], E, ass[mp], ads[mp], den, hsrcs[mp], out);
  }

  // semantic attention per group: ind = (mp0, mp1), org = (mp2, mp3)
  float* o_ind0 = out_all + (size_t)0 * N * HH;
  float* o_ind1 = out_all + (size_t)1 * N * HH;
  float* o_org0 = out_all + (size_t)2 * N * HH;
  float* o_org1 = out_all + (size_t)3 * N * HH;

  score_kernel<<<nb_node, BS, 0, stream>>>(o_ind0, o_ind1, N, k_W, k_b, qv, score_all, flag);
  score_kernel<<<nb_node, BS, 0, stream>>>(o_org0, o_org1, N, k_W, k_b, qv, score_all + 2, flag);

  pred_kernel<<<nb_node, BS, 0, stream>>>(o_ind0, o_ind1, N, score_all,
                                          lin_ind_W, lin_ind_b, out_f, flag);
  pred_kernel<<<nb_node, BS, 0, stream>>>(o_org0, o_org1, N, score_all + 2,
                                          lin_org_W, lin_org_b, out_f + N, flag);
}

// Round 4
// 1539.976 us; speedup vs baseline: 4.1839x; 4.1839x over previous
//
#include <hip/hip_runtime.h>

#define HH 8
#define FIN 64

// ---------- helpers ----------
__device__ __forceinline__ float b2f(unsigned short u) {
  union { unsigned int i; float f; } x;
  x.i = ((unsigned int)u) << 16;
  return x.f;
}

__device__ __forceinline__ float lrelu(float x) { return x > 0.f ? x : 0.2f * x; }

// dtype-agnostic scalar load: isf=1 -> fp32 array, isf=0 -> bf16 array
__device__ __forceinline__ float ld(const void* p, int i, int isf) {
  return isf ? ((const float*)p)[i] : b2f(((const unsigned short*)p)[i]);
}

// ---------- dtype detection ----------
// Interpret first 2048 u16 of x as bf16. True bf16 ~N(0,1): exponent field
// < 0x90 always. fp32 read as u16 pairs: even slots are mantissa garbage,
// ~43% have exponent-field >= 0x90. Flag fp32 if count >= 8.
__global__ void detect_kernel(const unsigned short* __restrict__ x, int* __restrict__ flag) {
  __shared__ int s[256];
  int t = threadIdx.x;
  int cnt = 0;
  for (int i = t; i < 2048; i += 256) {
    int e = (x[i] >> 7) & 0xFF;
    if (e >= 0x90) cnt++;
  }
  s[t] = cnt;
  __syncthreads();
  for (int k = 128; k > 0; k >>= 1) {
    if (t < k) s[t] += s[t + k];
    __syncthreads();
  }
  if (t == 0) flag[0] = (s[0] >= 8) ? 1 : 0;
}

// ---------- fill ----------
__global__ void fill_u32(unsigned int* __restrict__ p, long long n, unsigned int v) {
  long long i = (long long)blockIdx.x * blockDim.x + threadIdx.x;
  if (i < n) p[i] = v;
}

// ---------- projection: h = x @ W + b, plus up to 3 attention dot-products ----------
__global__ void proj_kernel(const void* __restrict__ x,
                            const void* __restrict__ W,
                            const void* __restrict__ b,
                            float* __restrict__ h, int N,
                            const void* __restrict__ a0v, float* __restrict__ s0,
                            const void* __restrict__ a1v, float* __restrict__ s1,
                            const void* __restrict__ a2v, float* __restrict__ s2,
                            const int* __restrict__ flag) {
  __shared__ float Wl[FIN][HH];
  __shared__ float bl[HH];
  __shared__ float al[3][HH];
  int isf = flag[0];
  int t = threadIdx.x;
  for (int i = t; i < FIN * HH; i += blockDim.x) Wl[i >> 3][i & 7] = ld(W, i, isf);
  if (t < HH) {
    bl[t] = ld(b, t, isf);
    al[0][t] = a0v ? ld(a0v, t, isf) : 0.f;
    al[1][t] = a1v ? ld(a1v, t, isf) : 0.f;
    al[2][t] = a2v ? ld(a2v, t, isf) : 0.f;
  }
  __syncthreads();
  int n = blockIdx.x * blockDim.x + t;
  if (n >= N) return;
  float acc[HH];
#pragma unroll
  for (int j = 0; j < HH; ++j) acc[j] = bl[j];
  if (isf) {
    const float4* xr = (const float4*)((const float*)x + (size_t)n * FIN);
#pragma unroll
    for (int v = 0; v < FIN / 4; ++v) {
      float4 p = xr[v];
      float f4[4] = {p.x, p.y, p.z, p.w};
#pragma unroll
      for (int k = 0; k < 4; ++k) {
        int f = v * 4 + k;
#pragma unroll
        for (int j = 0; j < HH; ++j) acc[j] += f4[k] * Wl[f][j];
      }
    }
  } else {
    const uint4* xr = (const uint4*)((const unsigned short*)x + (size_t)n * FIN);
#pragma unroll
    for (int v = 0; v < FIN / 8; ++v) {
      uint4 p = xr[v];
      unsigned int w[4] = {p.x, p.y, p.z, p.w};
#pragma unroll
      for (int k = 0; k < 4; ++k) {
        float f0 = __uint_as_float(w[k] << 16);
        float f1 = __uint_as_float(w[k] & 0xFFFF0000u);
        int f = v * 8 + k * 2;
#pragma unroll
        for (int j = 0; j < HH; ++j) acc[j] += f0 * Wl[f][j];
#pragma unroll
        for (int j = 0; j < HH; ++j) acc[j] += f1 * Wl[f + 1][j];
      }
    }
  }
  float* hn = h + (size_t)n * HH;
#pragma unroll
  for (int j = 0; j < HH; ++j) hn[j] = acc[j];
  float d0 = 0.f, d1 = 0.f, d2 = 0.f;
#pragma unroll
  for (int j = 0; j < HH; ++j) {
    d0 += acc[j] * al[0][j];
    d1 += acc[j] * al[1][j];
    d2 += acc[j] * al[2][j];
  }
  if (s0) s0[n] = d0;
  if (s1) s1[n] = d1;
  if (s2) s2[n] = d2;
}

// ---------- fused GAT edge pass: unnormalized accumulate ----------
// out[c] += exp(lrelu(as[r]+ad[c])) * h_src[r];  den[c] += exp(...)
// Normalization (/ (den+1e-16)) happens in the consumers.
__global__ void edge_fused(const int* __restrict__ ei, int E,
                           const float* __restrict__ as, const float* __restrict__ ad,
                           const float* __restrict__ h_src,
                           float* __restrict__ den, float* __restrict__ out) {
  long long t = (long long)blockIdx.x * blockDim.x + threadIdx.x;
  int e = (int)(t >> 3);
  if (e >= E) return;
  int j = (int)(t & 7);
  int r = ei[e], c = ei[E + e];
  float a = lrelu(as[r] + ad[c]);
  float ex = __expf(a);
  if (j == 0) atomicAdd(&den[c], ex);
  atomicAdd(&out[(size_t)c * HH + j], ex * h_src[(size_t)r * HH + j]);
}

// ---------- semantic attention score: sum_n tanh(relu(o[n]/den) @ kW + kb) . q ----------
__global__ void score_kernel(const float* __restrict__ o0, const float* __restrict__ d0,
                             const float* __restrict__ o1, const float* __restrict__ d1,
                             int N,
                             const void* __restrict__ kW,
                             const void* __restrict__ kb,
                             const void* __restrict__ qv,
                             float* __restrict__ score,
                             const int* __restrict__ flag) {
  __shared__ float kWl[HH][HH];
  __shared__ float kbl[HH], ql[HH];
  __shared__ float red0[256], red1[256];
  int isf = flag[0];
  int t = threadIdx.x;
  if (t < HH * HH) kWl[t >> 3][t & 7] = ld(kW, t, isf);
  if (t < HH) { kbl[t] = ld(kb, t, isf); ql[t] = ld(qv, t, isf); }
  __syncthreads();
  int n = blockIdx.x * blockDim.x + t;
  float s0 = 0.f, s1 = 0.f;
  if (n < N) {
    const float* p0 = o0 + (size_t)n * HH;
    const float* p1 = o1 + (size_t)n * HH;
    float i0 = 1.f / (d0[n] + 1e-16f);
    float i1 = 1.f / (d1[n] + 1e-16f);
    float v0[HH], v1[HH];
#pragma unroll
    for (int j = 0; j < HH; ++j) { v0[j] = fmaxf(p0[j] * i0, 0.f); v1[j] = fmaxf(p1[j] * i1, 0.f); }
#pragma unroll
    for (int j = 0; j < HH; ++j) {
      float t0 = kbl[j], t1 = kbl[j];
#pragma unroll
      for (int i = 0; i < HH; ++i) { t0 += v0[i] * kWl[i][j]; t1 += v1[i] * kWl[i][j]; }
      s0 += tanhf(t0) * ql[j];
      s1 += tanhf(t1) * ql[j];
    }
  }
  red0[t] = s0; red1[t] = s1;
  __syncthreads();
  for (int s = 128; s > 0; s >>= 1) {
    if (t < s) { red0[t] += red0[t + s]; red1[t] += red1[t + s]; }
    __syncthreads();
  }
  if (t == 0) { atomicAdd(&score[0], red0[0]); atomicAdd(&score[1], red1[0]); }
}

// ---------- softmax over 2 metapaths + prediction head (fp32 output) ----------
__global__ void pred_kernel(const float* __restrict__ o0, const float* __restrict__ d0,
                            const float* __restrict__ o1, const float* __restrict__ d1,
                            int N,
                            const float* __restrict__ score,
                            const void* __restrict__ linW,
                            const void* __restrict__ linb,
                            float* __restrict__ outp,
                            const int* __restrict__ flag) {
  int isf = flag[0];
  int n = blockIdx.x * blockDim.x + threadIdx.x;
  if (n >= N) return;
  float s0 = score[0] / (float)N, s1 = score[1] / (float)N;
  float mx = fmaxf(s0, s1);
  float e0 = __expf(s0 - mx), e1 = __expf(s1 - mx);
  float inv = 1.f / (e0 + e1);
  float a0 = e0 * inv, a1 = e1 * inv;
  const float* p0 = o0 + (size_t)n * HH;
  const float* p1 = o1 + (size_t)n * HH;
  float i0 = 1.f / (d0[n] + 1e-16f);
  float i1 = 1.f / (d1[n] + 1e-16f);
  float acc = ld(linb, 0, isf);
#pragma unroll
  for (int j = 0; j < HH; ++j) {
    float z = a0 * fmaxf(p0[j] * i0, 0.f) + a1 * fmaxf(p1[j] * i1, 0.f);
    acc += z * ld(linW, j, isf);
  }
  outp[n] = 1.f / (1.f + __expf(-acc));
}

// ---------- launch ----------
extern "C" void kernel_launch(void* const* d_in, const int* in_sizes, int n_in,
                              void* d_out, int out_size, void* d_ws, size_t ws_size,
                              hipStream_t stream) {
  const int N = in_sizes[0] / FIN;

  const void* x_ind = d_in[0];
  const void* x_org = d_in[1];
  const void* x_ext = d_in[2];
  const int* ei_io = (const int*)d_in[3];  int E_io = in_sizes[3] / 2;  // ind->org
  const int* ei_oi = (const int*)d_in[4];  int E_oi = in_sizes[4] / 2;  // org->ind
  const int* ei_ei = (const int*)d_in[5];  int E_ei = in_sizes[5] / 2;  // ext->ind
  const int* ei_eo = (const int*)d_in[6];  int E_eo = in_sizes[6] / 2;  // ext->org
  const void* W_ind = d_in[7];
  const void* b_ind = d_in[8];
  const void* W_org = d_in[9];
  const void* b_org = d_in[10];
  const void* W_ext = d_in[11];
  const void* b_ext = d_in[12];
  const void* att_src_io = d_in[13];
  const void* att_dst_io = d_in[14];
  const void* att_src_oi = d_in[15];
  const void* att_dst_oi = d_in[16];
  const void* att_src_ei = d_in[17];
  const void* att_dst_ei = d_in[18];
  const void* att_src_eo = d_in[19];
  const void* att_dst_eo = d_in[20];
  const void* k_W = d_in[21];
  const void* k_b = d_in[22];
  const void* qv  = d_in[23];
  const void* lin_ind_W = d_in[24];
  const void* lin_ind_b = d_in[25];
  const void* lin_org_W = d_in[26];
  const void* lin_org_b = d_in[27];

  float* out_f = (float*)d_out;

  // workspace layout (floats)
  float* ws = (float*)d_ws;
  size_t off = 0;
  float* h_ind = ws + off; off += (size_t)N * HH;
  float* h_org = ws + off; off += (size_t)N * HH;
  float* h_ext = ws + off; off += (size_t)N * HH;
  float* as_io = ws + off; off += N;   // h_ind . att_src_ind_org
  float* ad_oi = ws + off; off += N;   // h_ind . att_dst_org_ind
  float* ad_ei = ws + off; off += N;   // h_ind . att_dst_ext_ind
  float* as_oi = ws + off; off += N;   // h_org . att_src_org_ind
  float* ad_io = ws + off; off += N;   // h_org . att_dst_ind_org
  float* ad_eo = ws + off; off += N;   // h_org . att_dst_ext_org
  float* as_ei = ws + off; off += N;   // h_ext . att_src_ext_ind
  float* as_eo = ws + off; off += N;   // h_ext . att_src_ext_org
  float* den_all = ws + off; off += (size_t)4 * N;       // per-mp denom (unnormalized)
  float* out_all = ws + off; off += (size_t)4 * N * HH;  // per-mp unnormalized sums [N,8]
  float* score_all = ws + off; off += 4;                 // 2 groups x 2 metapaths
  int* flag = (int*)(ws + off); off += 1;                // dtype flag

  const int BS = 256;
  const int nb_node = (N + BS - 1) / BS;

  detect_kernel<<<1, BS, 0, stream>>>((const unsigned short*)x_ind, flag);

  // zero den_all, out_all, score_all (contiguous)
  {
    long long nz = (long long)4 * N + (long long)4 * N * HH + 4;
    fill_u32<<<(int)((nz + BS - 1) / BS), BS, 0, stream>>>((unsigned int*)den_all, nz, 0u);
  }

  // projections + per-node attention scalars
  proj_kernel<<<nb_node, BS, 0, stream>>>(x_ind, W_ind, b_ind, h_ind, N,
                                          att_src_io, as_io, att_dst_oi, ad_oi, att_dst_ei, ad_ei, flag);
  proj_kernel<<<nb_node, BS, 0, stream>>>(x_org, W_org, b_org, h_org, N,
                                          att_src_oi, as_oi, att_dst_io, ad_io, att_dst_eo, ad_eo, flag);
  proj_kernel<<<nb_node, BS, 0, stream>>>(x_ext, W_ext, b_ext, h_ext, N,
                                          att_src_ei, as_ei, att_src_eo, as_eo,
                                          (const void*)nullptr, (float*)nullptr, flag);

  // metapath table: mp0 org->ind, mp1 ext->ind, mp2 ind->org, mp3 ext->org
  const int* eis[4]      = {ei_oi, ei_ei, ei_io, ei_eo};
  int        Es[4]       = {E_oi, E_ei, E_io, E_eo};
  const float* ass[4]    = {as_oi, as_ei, as_io, as_eo};
  const float* ads[4]    = {ad_oi, ad_ei, ad_io, ad_eo};
  const float* hsrcs[4]  = {h_org, h_ext, h_ind, h_ext};

  for (int mp = 0; mp < 4; ++mp) {
    int E = Es[mp];
    float* den = den_all + (size_t)mp * N;
    float* out = out_all + (size_t)mp * N * HH;
    int nbE8 = (int)(((long long)E * HH + BS - 1) / BS);
    edge_fused<<<nbE8, BS, 0, stream>>>(eis[mp], E, ass[mp], ads[mp], hsrcs[mp], den, out);
  }

  // semantic attention per group: ind = (mp0, mp1), org = (mp2, mp3)
  float* o_ind0 = out_all + (size_t)0 * N * HH;
  float* o_ind1 = out_all + (size_t)1 * N * HH;
  float* o_org0 = out_all + (size_t)2 * N * HH;
  float* o_org1 = out_all + (size_t)3 * N * HH;
  float* d_ind0 = den_all + (size_t)0 * N;
  float* d_ind1 = den_all + (size_t)1 * N;
  float* d_org0 = den_all + (size_t)2 * N;
  float* d_org1 = den_all + (size_t)3 * N;

  score_kernel<<<nb_node, BS, 0, stream>>>(o_ind0, d_ind0, o_ind1, d_ind1, N,
                                           k_W, k_b, qv, score_all, flag);
  score_kernel<<<nb_node, BS, 0, stream>>>(o_org0, d_org0, o_org1, d_org1, N,
                                           k_W, k_b, qv, score_all + 2, flag);

  pred_kernel<<<nb_node, BS, 0, stream>>>(o_ind0, d_ind0, o_ind1, d_ind1, N, score_all,
                                          lin_ind_W, lin_ind_b, out_f, flag);
  pred_kernel<<<nb_node, BS, 0, stream>>>(o_org0, d_org0, o_org1, d_org1, N, score_all + 2,
                                          lin_org_W, lin_org_b, out_f + N, flag);
}